// Round 1
// baseline (291.183 us; speedup 1.0000x reference)
//
#include <hip/hip_runtime.h>

#define HH 512
#define WW 512
#define HW (HH*WW)
#define TS 32      // output tile
#define RT 48      // raw tile: TS + 2*8
#define AT 40      // ac tile:  TS + 2*4
#define EPV 1e-20f

// Box window for center (y,x): rows y-3..y+4, cols x-3..x+4 (zero padded).
// In a tile with origin (ty0-4, tx0-4) [index p,q], center = (p,q) means image
// (ty0-4+p, tx0-4+q); its window = tile rows p-3+4=p+1 .. p+8 relative to a
// raw tile with origin (ty0-8, tx0-8). Everywhere below: offsets d=1..8.

__global__ __launch_bounds__(256) void prep_kernel(
    const float* __restrict__ outs, const float* __restrict__ labs,
    float* __restrict__ ac, float* __restrict__ bc,
    float* __restrict__ sii, float* __restrict__ sjj)
{
    __shared__ float raw[RT][RT];     // raw input tile, halo 8
    __shared__ float hsb[RT][AT];     // horizontal 8-sums of raw
    __shared__ float acs[AT][AT];     // centered values, halo 4
    __shared__ float hs2[AT][TS];     // horizontal 8-sums of acs^2

    const int z = blockIdx.z;
    const float* src;
    float* dst_c;
    float* dst_s;
    if (z < 24) { src = outs + z*HW;        dst_c = ac + z*HW;        dst_s = sii + z*HW; }
    else        { int t = z-24; src = labs + t*HW; dst_c = bc + t*HW; dst_s = sjj + t*HW; }

    const int ty0 = blockIdx.y * TS;
    const int tx0 = blockIdx.x * TS;
    const int tid = threadIdx.x;

    // ---- load raw 48x48 tile (zero OOB) ----
    for (int idx = tid; idx < RT*RT; idx += 256) {
        int r = idx / RT, c = idx % RT;
        int gy = ty0 - 8 + r, gx = tx0 - 8 + c;
        float v = 0.f;
        if (gy >= 0 && gy < HH && gx >= 0 && gx < WW) v = src[gy*WW + gx];
        raw[r][c] = v;
    }
    __syncthreads();

    // ---- horizontal 8-sums: hsb[r][q] = sum raw[r][q+1..q+8] ----
    for (int idx = tid; idx < RT*AT; idx += 256) {
        int r = idx / AT, q = idx % AT;
        float s = 0.f;
        #pragma unroll
        for (int d = 1; d <= 8; ++d) s += raw[r][q+d];
        hsb[r][q] = s;
    }
    __syncthreads();

    // ---- vertical 8-sums -> box mean; acs = raw - mean (0 if OOB) ----
    for (int idx = tid; idx < AT*AT; idx += 256) {
        int p = idx / AT, q = idx % AT;
        float s = 0.f;
        #pragma unroll
        for (int d = 1; d <= 8; ++d) s += hsb[p+d][q];
        int gy = ty0 - 4 + p, gx = tx0 - 4 + q;
        float v = 0.f;
        if (gy >= 0 && gy < HH && gx >= 0 && gx < WW)
            v = raw[p+4][q+4] - s * (1.0f/64.0f);
        acs[p][q] = v;
    }
    __syncthreads();

    // ---- write centered values (center 32x32) ----
    for (int idx = tid; idx < TS*TS; idx += 256) {
        int y = idx / TS, x = idx % TS;
        dst_c[(ty0+y)*WW + tx0+x] = acs[y+4][x+4];
    }

    // ---- horizontal 8-sums of acs^2 ----
    for (int idx = tid; idx < AT*TS; idx += 256) {
        int p = idx / TS, x = idx % TS;
        float s = 0.f;
        #pragma unroll
        for (int d = 1; d <= 8; ++d) { float v = acs[p][x+d]; s += v*v; }
        hs2[p][x] = s;
    }
    __syncthreads();

    // ---- vertical 8-sums -> sii (clamped) ----
    for (int idx = tid; idx < TS*TS; idx += 256) {
        int y = idx / TS, x = idx % TS;
        float s = 0.f;
        #pragma unroll
        for (int d = 1; d <= 8; ++d) s += hs2[y+d][x];
        dst_s[(ty0+y)*WW + tx0+x] = fmaxf(s, EPV);
    }
}

__global__ __launch_bounds__(256) void ncc_main_kernel(
    const float* __restrict__ ac, const float* __restrict__ bc,
    const float* __restrict__ sii, const float* __restrict__ sjj,
    float* __restrict__ out)
{
    __shared__ float at[AT][AT];
    __shared__ float bt[AT][AT];
    __shared__ float hs[AT][TS];
    __shared__ float wsum[4];

    const int z = blockIdx.z;          // b*6 + i
    const int b = z / 6;
    const int ty0 = blockIdx.y * TS;
    const int tx0 = blockIdx.x * TS;
    const int tid = threadIdx.x;

    const float* acp = ac  + z*HW;
    const float* sip = sii + z*HW;

    // load ac tile with halo 4 (zero OOB)
    for (int idx = tid; idx < AT*AT; idx += 256) {
        int p = idx / AT, q = idx % AT;
        int gy = ty0 - 4 + p, gx = tx0 - 4 + q;
        at[p][q] = (gy >= 0 && gy < HH && gx >= 0 && gx < WW) ? acp[gy*WW + gx] : 0.f;
    }

    // per-thread pixels: idx = k*256 + tid, y = idx>>5, x = idx&31
    float siir[4], m[4];
    #pragma unroll
    for (int k = 0; k < 4; ++k) {
        int idx = k*256 + tid;
        int y = idx >> 5, x = idx & 31;
        siir[k] = sip[(ty0+y)*WW + tx0+x];
        m[k] = -1.0f;
    }

    for (int j = 0; j < 4; ++j) {
        const float* bcp = bc  + (b*4 + j)*HW;
        const float* sjp = sjj + (b*4 + j)*HW;

        __syncthreads();   // prior hs reads done before bt/hs rewritten
        for (int idx = tid; idx < AT*AT; idx += 256) {
            int p = idx / AT, q = idx % AT;
            int gy = ty0 - 4 + p, gx = tx0 - 4 + q;
            bt[p][q] = (gy >= 0 && gy < HH && gx >= 0 && gx < WW) ? bcp[gy*WW + gx] : 0.f;
        }
        __syncthreads();

        // horizontal 8-sums of product
        for (int idx = tid; idx < AT*TS; idx += 256) {
            int p = idx / TS, x = idx % TS;
            float s = 0.f;
            #pragma unroll
            for (int d = 1; d <= 8; ++d) s += at[p][x+d] * bt[p][x+d];
            hs[p][x] = s;
        }
        __syncthreads();

        // vertical 8-sums -> sij -> cc -> running max
        #pragma unroll
        for (int k = 0; k < 4; ++k) {
            int idx = k*256 + tid;
            int y = idx >> 5, x = idx & 31;
            float s = 0.f;
            #pragma unroll
            for (int d = 1; d <= 8; ++d) s += hs[y+d][x];
            float sj = sjp[(ty0+y)*WW + tx0+x];
            float cc = s / (sqrtf(siir[k] * sj) + EPV);
            m[k] = fmaxf(m[k], cc);
        }
    }

    // X = 1 - clamp(m, -1, 1); m already >= -1
    float xs = 0.f;
    #pragma unroll
    for (int k = 0; k < 4; ++k) xs += 1.0f - fminf(m[k], 1.0f);

    // wave (64) reduce, then block reduce
    #pragma unroll
    for (int off = 32; off > 0; off >>= 1) xs += __shfl_down(xs, off);
    if ((tid & 63) == 0) wsum[tid >> 6] = xs;
    __syncthreads();
    if (tid == 0) {
        float s = wsum[0] + wsum[1] + wsum[2] + wsum[3];
        atomicAdd(&out[1 + z], s * (1.0f / (float)HW));
        atomicAdd(&out[0],     s * (1.0f / (24.0f * (float)HW)));
    }
}

extern "C" void kernel_launch(void* const* d_in, const int* in_sizes, int n_in,
                              void* d_out, int out_size, void* d_ws, size_t ws_size,
                              hipStream_t stream) {
    const float* outs = (const float*)d_in[0];   // (4,6,512,512)
    const float* labs = (const float*)d_in[1];   // (4,4,512,512)
    float* out = (float*)d_out;                  // 25 floats: [mean, 4x6 means]
    float* ws = (float*)d_ws;

    float* ac  = ws;                 // 24*HW
    float* bcw = ac  + 24*HW;        // 16*HW
    float* siw = bcw + 16*HW;        // 24*HW
    float* sjw = siw + 24*HW;        // 16*HW

    hipMemsetAsync(d_out, 0, out_size * sizeof(float), stream);

    prep_kernel<<<dim3(WW/TS, HH/TS, 40), 256, 0, stream>>>(outs, labs, ac, bcw, siw, sjw);
    ncc_main_kernel<<<dim3(WW/TS, HH/TS, 24), 256, 0, stream>>>(ac, bcw, siw, sjw, out);
}